// Round 3
// baseline (1822.264 us; speedup 1.0000x reference)
//
#include <hip/hip_runtime.h>
#include <stdint.h>
#include <math.h>

// ---------------- problem sizes ----------------
#define NB   64
#define LL   2000
#define CIN  4
#define NF   256
#define KW   13
#define NOUT 500
#define NH   8
#define DH   64
#define DMID 100
#define NCLS 2

// ---------------- ws layout ----------------
// fp32 stats region (float offsets): psum[64][256], psq[64][256],
// scale[256], shift[256], part[64][8][100]  -> 84480 floats = 337,920 B
#define OFF_PSUM   0
#define OFF_PSQ    16384
#define OFF_SCALE  32768
#define OFF_SHIFT  33024
#define OFF_PART   33280
// bf16 buffers (byte offsets). o aliases ymax (ymax dead after k_qkv).
#define BOFF_Q     337920ull
#define QKV_TSZ    32768000ull               // 64*8*500*64 * 2B
#define BOFF_K     (BOFF_Q + QKV_TSZ)
#define BOFF_V     (BOFF_K + QKV_TSZ)
#define BOFF_YM    (BOFF_V + QKV_TSZ)        // ymax[64][256][512] bf16 = 16,777,216 B
#define BOFF_O     BOFF_YM                   // o[64][500][512] bf16 = 32,768,000 B (overlaps ymax)
#define WS_NEED    (BOFF_O + 32768000ull)    // 131,409,920 B  (< 128 MiB)

// ---------------- bf16 helpers (RNE) ----------------
__device__ __forceinline__ float blo(uint32_t u) { return __uint_as_float(u << 16); }
__device__ __forceinline__ float bhi(uint32_t u) { return __uint_as_float(u & 0xFFFF0000u); }
__device__ __forceinline__ uint32_t f2bf1(float f) {
  uint32_t x = __float_as_uint(f);
  return (x + 0x7FFFu + ((x >> 16) & 1u)) >> 16;
}
__device__ __forceinline__ uint32_t pack2(float a, float b) {
  return f2bf1(a) | (f2bf1(b) << 16);
}

// =====================================================================
// Kernel 1: conv1d + per-channel sum/sumsq (pre-BN) + maxpool(4), fused.
// grid (64 b, 16 fgroups of 16 filters), block 512 (1 thread = 1 pooled pos)
// Writes pre-BN pooled max as bf16 [b][f][512-padded]. BN+ReLU commute with
// max (scale>0), applied later in k_qkv.
// =====================================================================
__global__ __launch_bounds__(512) void k_conv(const float* __restrict__ x,
                                              const float* __restrict__ cw,
                                              uint16_t* __restrict__ ymax,
                                              float* __restrict__ psum,
                                              float* __restrict__ psq) {
  const int b = blockIdx.x;
  const int fg = blockIdx.y;
  const int tid = threadIdx.x;
  const int n = tid;                // pooled position
  const bool act = (n < NOUT);
  const float* xb = x + (size_t)b * (LL * CIN);

  float4 xw[16];
#pragma unroll
  for (int i = 0; i < 16; ++i) {
    const int p = 4 * n - 6 + i;    // conv position l+k-6, l=4n..4n+3, i=j+k
    if (act && p >= 0 && p < LL)
      xw[i] = *(const float4*)(xb + (size_t)p * CIN);
    else
      xw[i] = make_float4(0.f, 0.f, 0.f, 0.f);
  }

  __shared__ float redS[8][16];
  __shared__ float redQ[8][16];
  const int wave = tid >> 6, lane = tid & 63;

  for (int fi = 0; fi < 16; ++fi) {
    const int f = fg * 16 + fi;
    const float* w = cw + (size_t)f * (CIN * KW);
    float wr[4][13];
#pragma unroll
    for (int c = 0; c < 4; ++c)
#pragma unroll
      for (int k = 0; k < 13; ++k) wr[c][k] = w[c * 13 + k];

    float a0 = 0.f, a1 = 0.f, a2 = 0.f, a3 = 0.f;
#pragma unroll
    for (int k = 0; k < 13; ++k) {
      const float4 p0 = xw[k + 0];
      const float4 p1 = xw[k + 1];
      const float4 p2 = xw[k + 2];
      const float4 p3 = xw[k + 3];
      a0 += wr[0][k] * p0.x + wr[1][k] * p0.y + wr[2][k] * p0.z + wr[3][k] * p0.w;
      a1 += wr[0][k] * p1.x + wr[1][k] * p1.y + wr[2][k] * p1.z + wr[3][k] * p1.w;
      a2 += wr[0][k] * p2.x + wr[1][k] * p2.y + wr[2][k] * p2.z + wr[3][k] * p2.w;
      a3 += wr[0][k] * p3.x + wr[1][k] * p3.y + wr[2][k] * p3.z + wr[3][k] * p3.w;
    }
    const float pm = fmaxf(fmaxf(a0, a1), fmaxf(a2, a3));
    if (act) ymax[((size_t)b * NF + f) * 512 + n] = (uint16_t)f2bf1(pm);

    float s  = act ? (a0 + a1 + a2 + a3) : 0.f;
    float q2 = act ? (a0 * a0 + a1 * a1 + a2 * a2 + a3 * a3) : 0.f;
#pragma unroll
    for (int off = 32; off >= 1; off >>= 1) {
      s  += __shfl_xor(s,  off, 64);
      q2 += __shfl_xor(q2, off, 64);
    }
    if (lane == 0) { redS[wave][fi] = s; redQ[wave][fi] = q2; }
  }
  __syncthreads();
  if (tid < 16) {
    float s = 0.f;
#pragma unroll
    for (int wv = 0; wv < 8; ++wv) s += redS[wv][tid];
    psum[b * NF + fg * 16 + tid] = s;
  } else if (tid < 32) {
    float s = 0.f;
#pragma unroll
    for (int wv = 0; wv < 8; ++wv) s += redQ[wv][tid - 16];
    psq[b * NF + fg * 16 + (tid - 16)] = s;
  }
}

// =====================================================================
// Kernel 2: fold BN batch stats into per-channel scale/shift.
// =====================================================================
__global__ void k_stats(const float* __restrict__ psum, const float* __restrict__ psq,
                        const float* __restrict__ gamma, const float* __restrict__ beta,
                        float* __restrict__ scale, float* __restrict__ shift) {
  const int f = threadIdx.x;
  float s = 0.f, q = 0.f;
  for (int b = 0; b < NB; ++b) { s += psum[b * NF + f]; q += psq[b * NF + f]; }
  const float inv = 1.0f / (float)(NB * LL);
  const float mean = s * inv;
  const float var = q * inv - mean * mean;
  const float sc = gamma[f] * rsqrtf(var + 1e-5f);
  scale[f] = sc;
  shift[f] = beta[f] - mean * sc;
}

// =====================================================================
// Kernel 3: QKV projection GEMM.  h[b,n,f] = relu(scale*ymax+shift) built
// on the fly from bf16 ymax.  grid (8 ntiles, 24 = {q,k,v}x8 heads, 64 b),
// block 256.  C-tile 64x64, micro 4x4, K=256 in 8 chunks of 32.  bf16 out.
// =====================================================================
__global__ __launch_bounds__(256) void k_qkv(const uint16_t* __restrict__ ymax,
     const float* __restrict__ scale, const float* __restrict__ shift,
     const float* __restrict__ Wq, const float* __restrict__ bq,
     const float* __restrict__ Wk, const float* __restrict__ bk,
     const float* __restrict__ Wv, const float* __restrict__ bv,
     uint16_t* __restrict__ qb, uint16_t* __restrict__ kb, uint16_t* __restrict__ vb) {
  const int nt = blockIdx.x;
  const int g  = blockIdx.y;
  const int b  = blockIdx.z;
  const int which = g >> 3, h = g & 7;
  const int n0 = nt * 64;
  const float* W    = (which == 0 ? Wq : which == 1 ? Wk : Wv) + (size_t)h * NF * DH;
  const float* bias = (which == 0 ? bq : which == 1 ? bk : bv) + h * DH;
  uint16_t* out = (which == 0 ? qb : which == 1 ? kb : vb) + (size_t)(b * NH + h) * NOUT * DH;

  __shared__ float As[32][68];   // [k][n-local]
  __shared__ float Bs[32][68];   // [k][d]
  const int tid = threadIdx.x;
  const int tr = tid >> 4, tc = tid & 15;
  float acc[4][4] = {};

  for (int kc = 0; kc < 8; ++kc) {
    {
      const int r = tid >> 3, c8 = (tid & 7) * 8;
      const int f = kc * 32 + r;
      const float sc = scale[f], sh = shift[f];
      const uint16_t* src = ymax + ((size_t)b * NF + f) * 512 + n0 + c8;  // padded row: in-bounds
      const uint4 u = *(const uint4*)src;
      As[r][c8 + 0] = fmaxf(sc * blo(u.x) + sh, 0.f);
      As[r][c8 + 1] = fmaxf(sc * bhi(u.x) + sh, 0.f);
      As[r][c8 + 2] = fmaxf(sc * blo(u.y) + sh, 0.f);
      As[r][c8 + 3] = fmaxf(sc * bhi(u.y) + sh, 0.f);
      As[r][c8 + 4] = fmaxf(sc * blo(u.z) + sh, 0.f);
      As[r][c8 + 5] = fmaxf(sc * bhi(u.z) + sh, 0.f);
      As[r][c8 + 6] = fmaxf(sc * blo(u.w) + sh, 0.f);
      As[r][c8 + 7] = fmaxf(sc * bhi(u.w) + sh, 0.f);
      const float* wsrc = W + (size_t)f * DH + c8;
      *(float4*)&Bs[r][c8]     = *(const float4*)wsrc;
      *(float4*)&Bs[r][c8 + 4] = *(const float4*)(wsrc + 4);
    }
    __syncthreads();
#pragma unroll
    for (int k = 0; k < 32; ++k) {
      const float4 a = *(const float4*)&As[k][tr * 4];
      const float4 w = *(const float4*)&Bs[k][tc * 4];
      const float ar[4] = {a.x, a.y, a.z, a.w};
      const float wr[4] = {w.x, w.y, w.z, w.w};
#pragma unroll
      for (int ii = 0; ii < 4; ++ii)
#pragma unroll
        for (int jj = 0; jj < 4; ++jj) acc[ii][jj] += ar[ii] * wr[jj];
    }
    __syncthreads();
  }
  const float4 bv4 = *(const float4*)(bias + tc * 4);
#pragma unroll
  for (int ii = 0; ii < 4; ++ii) {
    const int nn = n0 + tr * 4 + ii;
    if (nn < NOUT) {
      uint2 st;
      st.x = pack2(acc[ii][0] + bv4.x, acc[ii][1] + bv4.y);
      st.y = pack2(acc[ii][2] + bv4.z, acc[ii][3] + bv4.w);
      *(uint2*)(out + (size_t)nn * DH + tc * 4) = st;
    }
  }
}

// =====================================================================
// Kernel 4: fused attention (flash-style, fp32 compute, bf16 I/O).
// grid (8 qtiles, 8 h, 64 b), block 256.  Q/K/V/P 64x64 fp32 tiles in LDS
// (64 KB), XOR-swizzled (col4 ^= row>>2).  Bias inline: (4|m-n|+3)/1999.
// =====================================================================
__device__ __forceinline__ float4 ld4sw(const float (*A)[64], int row, int d) {
  const int c4 = ((d >> 2) ^ (row >> 2)) & 15;
  return *(const float4*)&A[row][c4 << 2];
}
__device__ __forceinline__ void st4sw(float (*A)[64], int row, int d, float4 v) {
  const int c4 = ((d >> 2) ^ (row >> 2)) & 15;
  *(float4*)&A[row][c4 << 2] = v;
}

__global__ __launch_bounds__(256) void k_attn(const uint16_t* __restrict__ qb,
                                              const uint16_t* __restrict__ kb,
                                              const uint16_t* __restrict__ vb,
                                              uint16_t* __restrict__ ob) {
  const int qt = blockIdx.x;
  const int h  = blockIdx.y;
  const int b  = blockIdx.z;
  const int n0 = qt * 64;
  __shared__ float Qs[64][64], Ks[64][64], Vs[64][64], Ps[64][64];
  const int tid = threadIdx.x;
  const int tr = tid >> 4, tc = tid & 15;
  const size_t basebh = (size_t)(b * NH + h) * NOUT * DH;

  {  // stage Q tile (row-clamped; clamped rows are never stored)
    const int r = tid >> 2, dq = (tid & 3) * 16;
    const int nn = min(n0 + r, NOUT - 1);
    const uint16_t* src = qb + basebh + (size_t)nn * DH + dq;
    const uint4 a = *(const uint4*)src;
    const uint4 c = *(const uint4*)(src + 8);
    st4sw(Qs, r, dq +  0, make_float4(blo(a.x), bhi(a.x), blo(a.y), bhi(a.y)));
    st4sw(Qs, r, dq +  4, make_float4(blo(a.z), bhi(a.z), blo(a.w), bhi(a.w)));
    st4sw(Qs, r, dq +  8, make_float4(blo(c.x), bhi(c.x), blo(c.y), bhi(c.y)));
    st4sw(Qs, r, dq + 12, make_float4(blo(c.z), bhi(c.z), blo(c.w), bhi(c.w)));
  }

  float oacc[4][4] = {};
  float mrow[4] = {-1e30f, -1e30f, -1e30f, -1e30f};
  float lrow[4] = {};

  for (int kc = 0; kc < 8; ++kc) {
    const int kv0 = kc * 64;
    __syncthreads();               // prev PV done (also covers Q staging at kc=0)
    {
      const int r = tid >> 2, dq = (tid & 3) * 16;
      const int nn = min(kv0 + r, NOUT - 1);
      const uint16_t* ksrc = kb + basebh + (size_t)nn * DH + dq;
      const uint16_t* vsrc = vb + basebh + (size_t)nn * DH + dq;
      const uint4 ka = *(const uint4*)ksrc;
      const uint4 kc4 = *(const uint4*)(ksrc + 8);
      const uint4 va = *(const uint4*)vsrc;
      const uint4 vc = *(const uint4*)(vsrc + 8);
      st4sw(Ks, r, dq +  0, make_float4(blo(ka.x), bhi(ka.x), blo(ka.y), bhi(ka.y)));
      st4sw(Ks, r, dq +  4, make_float4(blo(ka.z), bhi(ka.z), blo(ka.w), bhi(ka.w)));
      st4sw(Ks, r, dq +  8, make_float4(blo(kc4.x), bhi(kc4.x), blo(kc4.y), bhi(kc4.y)));
      st4sw(Ks, r, dq + 12, make_float4(blo(kc4.z), bhi(kc4.z), blo(kc4.w), bhi(kc4.w)));
      st4sw(Vs, r, dq +  0, make_float4(blo(va.x), bhi(va.x), blo(va.y), bhi(va.y)));
      st4sw(Vs, r, dq +  4, make_float4(blo(va.z), bhi(va.z), blo(va.w), bhi(va.w)));
      st4sw(Vs, r, dq +  8, make_float4(blo(vc.x), bhi(vc.x), blo(vc.y), bhi(vc.y)));
      st4sw(Vs, r, dq + 12, make_float4(blo(vc.z), bhi(vc.z), blo(vc.w), bhi(vc.w)));
    }
    __syncthreads();

    float s[4][4] = {};
#pragma unroll
    for (int d = 0; d < 64; d += 4) {
      float4 qv[4], kv[4];
#pragma unroll
      for (int ii = 0; ii < 4; ++ii) qv[ii] = ld4sw(Qs, tr * 4 + ii, d);
#pragma unroll
      for (int jj = 0; jj < 4; ++jj) kv[jj] = ld4sw(Ks, tc * 4 + jj, d);
#pragma unroll
      for (int ii = 0; ii < 4; ++ii)
#pragma unroll
        for (int jj = 0; jj < 4; ++jj)
          s[ii][jj] += qv[ii].x * kv[jj].x + qv[ii].y * kv[jj].y +
                       qv[ii].z * kv[jj].z + qv[ii].w * kv[jj].w;
    }

    // online softmax update (row reduce = shfl over the 16 tc lanes)
#pragma unroll
    for (int ii = 0; ii < 4; ++ii) {
      const int nq = n0 + tr * 4 + ii;
      float sv[4];
      float rm = -1e30f;
#pragma unroll
      for (int jj = 0; jj < 4; ++jj) {
        const int nk = kv0 + tc * 4 + jj;
        float val = s[ii][jj] * 0.125f - (4.0f * fabsf((float)(nq - nk)) + 3.0f) * (1.0f / 1999.0f);
        if (nk >= NOUT) val = -1e30f;
        sv[jj] = val;
        rm = fmaxf(rm, val);
      }
      rm = fmaxf(rm, __shfl_xor(rm, 1, 64));
      rm = fmaxf(rm, __shfl_xor(rm, 2, 64));
      rm = fmaxf(rm, __shfl_xor(rm, 4, 64));
      rm = fmaxf(rm, __shfl_xor(rm, 8, 64));
      const float mnew = fmaxf(mrow[ii], rm);
      const float corr = __expf(mrow[ii] - mnew);
      mrow[ii] = mnew;
      const float p0 = __expf(sv[0] - mnew);
      const float p1 = __expf(sv[1] - mnew);
      const float p2 = __expf(sv[2] - mnew);
      const float p3 = __expf(sv[3] - mnew);
      st4sw(Ps, tr * 4 + ii, tc * 4, make_float4(p0, p1, p2, p3));
      float rs = p0 + p1 + p2 + p3;
      rs += __shfl_xor(rs, 1, 64);
      rs += __shfl_xor(rs, 2, 64);
      rs += __shfl_xor(rs, 4, 64);
      rs += __shfl_xor(rs, 8, 64);
      lrow[ii] = lrow[ii] * corr + rs;
#pragma unroll
      for (int jj = 0; jj < 4; ++jj) oacc[ii][jj] *= corr;
    }
    __syncthreads();

    // PV: oacc[ii][dd] += sum_j P[i][j] * V[j][dd]
#pragma unroll
    for (int j = 0; j < 64; j += 4) {
      float4 p4[4], v4[4];
#pragma unroll
      for (int ii = 0; ii < 4; ++ii) p4[ii] = ld4sw(Ps, tr * 4 + ii, j);
#pragma unroll
      for (int t = 0; t < 4; ++t) v4[t] = ld4sw(Vs, j + t, tc * 4);
      float pr[4][4], vr[4][4];
#pragma unroll
      for (int ii = 0; ii < 4; ++ii) {
        pr[ii][0] = p4[ii].x; pr[ii][1] = p4[ii].y; pr[ii][2] = p4[ii].z; pr[ii][3] = p4[ii].w;
      }
#pragma unroll
      for (int t = 0; t < 4; ++t) {
        vr[t][0] = v4[t].x; vr[t][1] = v4[t].y; vr[t][2] = v4[t].z; vr[t][3] = v4[t].w;
      }
#pragma unroll
      for (int ii = 0; ii < 4; ++ii)
#pragma unroll
        for (int dd = 0; dd < 4; ++dd)
          oacc[ii][dd] += pr[ii][0] * vr[0][dd] + pr[ii][1] * vr[1][dd] +
                          pr[ii][2] * vr[2][dd] + pr[ii][3] * vr[3][dd];
    }
  }

#pragma unroll
  for (int ii = 0; ii < 4; ++ii) {
    const int nn = n0 + tr * 4 + ii;
    if (nn < NOUT) {
      const float inv = 1.0f / lrow[ii];
      uint2 st;
      st.x = pack2(oacc[ii][0] * inv, oacc[ii][1] * inv);
      st.y = pack2(oacc[ii][2] * inv, oacc[ii][3] * inv);
      // o layout: [B][NOUT][H*DH] — head-concat layout for the Wm GEMM
      *(uint2*)(ob + ((size_t)b * NOUT + nn) * (NH * DH) + h * DH + tc * 4) = st;
    }
  }
}

// =====================================================================
// Kernel 5: m = relu(o @ Wm + bm); partial position-sum per (b, ntile).
// grid (8 ntiles, 2 coltiles, 64 b), block 256.  K=512 in 16 chunks.
// =====================================================================
__global__ __launch_bounds__(256) void k_mhl(const uint16_t* __restrict__ ob,
                                             const float* __restrict__ Wm,
                                             const float* __restrict__ bm,
                                             float* __restrict__ part) {
  const int nt = blockIdx.x;
  const int ct = blockIdx.y;
  const int b  = blockIdx.z;
  const int n0 = nt * 64, c0 = ct * 64;
  __shared__ float As[32][68];   // [k][n-local] (transposed on store)
  __shared__ float Bs[32][68];   // [k][c]
  __shared__ float lfeat[64];
  const int tid = threadIdx.x;
  const int tr = tid >> 4, tc = tid & 15;
  if (tid < 64) lfeat[tid] = 0.f;
  float acc[4][4] = {};

  for (int kc = 0; kc < 16; ++kc) {
    {
      const int nl = tid >> 2, kq = (tid & 3) * 8;
      const int nn = min(n0 + nl, NOUT - 1);
      const uint16_t* src = ob + ((size_t)b * NOUT + nn) * (NH * DH) + kc * 32 + kq;
      const uint4 u = *(const uint4*)src;
      As[kq + 0][nl] = blo(u.x); As[kq + 1][nl] = bhi(u.x);
      As[kq + 2][nl] = blo(u.y); As[kq + 3][nl] = bhi(u.y);
      As[kq + 4][nl] = blo(u.z); As[kq + 5][nl] = bhi(u.z);
      As[kq + 6][nl] = blo(u.w); As[kq + 7][nl] = bhi(u.w);
      const int r = tid >> 3, c8 = (tid & 7) * 8;
      const int kk = kc * 32 + r;
#pragma unroll
      for (int i = 0; i < 8; ++i) {
        const int c = c0 + c8 + i;
        Bs[r][c8 + i] = (c < DMID) ? Wm[(size_t)kk * DMID + c] : 0.f;
      }
    }
    __syncthreads();
#pragma unroll
    for (int k = 0; k < 32; ++k) {
      const float4 a = *(const float4*)&As[k][tr * 4];
      const float4 w = *(const float4*)&Bs[k][tc * 4];
      const float ar[4] = {a.x, a.y, a.z, a.w};
      const float wr[4] = {w.x, w.y, w.z, w.w};
#pragma unroll
      for (int ii = 0; ii < 4; ++ii)
#pragma unroll
        for (int jj = 0; jj < 4; ++jj) acc[ii][jj] += ar[ii] * wr[jj];
    }
    __syncthreads();
  }

  float colsum[4] = {};
#pragma unroll
  for (int jj = 0; jj < 4; ++jj) {
    const int c = c0 + tc * 4 + jj;
    const float bb = (c < DMID) ? bm[c] : 0.f;
#pragma unroll
    for (int ii = 0; ii < 4; ++ii) {
      const int nn = n0 + tr * 4 + ii;
      if (nn < NOUT && c < DMID) colsum[jj] += fmaxf(acc[ii][jj] + bb, 0.f);
    }
  }
#pragma unroll
  for (int jj = 0; jj < 4; ++jj) atomicAdd(&lfeat[tc * 4 + jj], colsum[jj]);
  __syncthreads();
  if (tid < 64 && c0 + tid < DMID)
    part[((size_t)b * 8 + nt) * DMID + c0 + tid] = lfeat[tid];
}

// =====================================================================
// Kernel 6: final readout: sum partials, normalize over 100 feats, @Wo+bo.
// =====================================================================
__global__ void k_head(const float* __restrict__ part, const float* __restrict__ Wo,
                       const float* __restrict__ bo, float* __restrict__ out) {
  const int b = threadIdx.x;  // 64 threads
  float s1 = 0.f;
  for (int c = 0; c < DMID; ++c) {
    float v = 0.f;
    for (int t = 0; t < 8; ++t) v += part[((size_t)b * 8 + t) * DMID + c];
    s1 += v;
  }
  const float mean = s1 / (float)DMID;
  float s2 = 0.f;
  for (int c = 0; c < DMID; ++c) {
    float v = 0.f;
    for (int t = 0; t < 8; ++t) v += part[((size_t)b * 8 + t) * DMID + c];
    const float d = v - mean;
    s2 += d * d;
  }
  const float inv = 1.0f / (sqrtf(s2 / (float)DMID) + 1e-6f);
  float o0 = bo[0], o1 = bo[1];
  for (int c = 0; c < DMID; ++c) {
    float v = 0.f;
    for (int t = 0; t < 8; ++t) v += part[((size_t)b * 8 + t) * DMID + c];
    const float nz = (v - mean) * inv;
    o0 += nz * Wo[c * 2 + 0];
    o1 += nz * Wo[c * 2 + 1];
  }
  out[b * 2 + 0] = o0;
  out[b * 2 + 1] = o1;
}

// =====================================================================
extern "C" void kernel_launch(void* const* d_in, const int* in_sizes, int n_in,
                              void* d_out, int out_size, void* d_ws, size_t ws_size,
                              hipStream_t stream) {
  (void)in_sizes; (void)n_in; (void)out_size;
  const float* x     = (const float*)d_in[0];
  const float* cw    = (const float*)d_in[1];
  const float* gamma = (const float*)d_in[2];
  const float* beta  = (const float*)d_in[3];
  const float* Wq    = (const float*)d_in[4];
  const float* bq    = (const float*)d_in[5];
  const float* Wk    = (const float*)d_in[6];
  const float* bk    = (const float*)d_in[7];
  const float* Wv    = (const float*)d_in[8];
  const float* bv    = (const float*)d_in[9];
  const float* Wm    = (const float*)d_in[10];
  const float* bm    = (const float*)d_in[11];
  const float* Wo    = (const float*)d_in[12];
  const float* bo    = (const float*)d_in[13];
  float* out = (float*)d_out;

  if (ws_size < WS_NEED) return;  // ws too small: fail loudly (poison stays)

  float* wsf = (float*)d_ws;
  float* psum  = wsf + OFF_PSUM;
  float* psq   = wsf + OFF_PSQ;
  float* scale = wsf + OFF_SCALE;
  float* shift = wsf + OFF_SHIFT;
  float* partf = wsf + OFF_PART;
  uint16_t* qbuf = (uint16_t*)((char*)d_ws + BOFF_Q);
  uint16_t* kbuf = (uint16_t*)((char*)d_ws + BOFF_K);
  uint16_t* vbuf = (uint16_t*)((char*)d_ws + BOFF_V);
  uint16_t* ymax = (uint16_t*)((char*)d_ws + BOFF_YM);
  uint16_t* obuf = (uint16_t*)((char*)d_ws + BOFF_O);   // aliases ymax (dead by then)

  k_conv <<<dim3(NB, 16), 512, 0, stream>>>(x, cw, ymax, psum, psq);
  k_stats<<<1, NF, 0, stream>>>(psum, psq, gamma, beta, scale, shift);
  k_qkv  <<<dim3(8, 24, NB), 256, 0, stream>>>(ymax, scale, shift, Wq, bq, Wk, bk, Wv, bv,
                                               qbuf, kbuf, vbuf);
  k_attn <<<dim3(8, NH, NB), 256, 0, stream>>>(qbuf, kbuf, vbuf, obuf);
  k_mhl  <<<dim3(8, 2, NB), 256, 0, stream>>>(obuf, Wm, bm, partf);
  k_head <<<1, NB, 0, stream>>>(partf, Wo, bo, out);
}

// Round 5
// 690.310 us; speedup vs baseline: 2.6398x; 2.6398x over previous
//
#include <hip/hip_runtime.h>
#include <stdint.h>
#include <math.h>

// ---------------- problem sizes ----------------
#define NB   64
#define LL   2000
#define CIN  4
#define NF   256
#define KW   13
#define NOUT 500
#define NH   8
#define DH   64
#define DMID 100
#define NCLS 2

// ---------------- ws layout (byte offsets) ----------------
// stats fp32 (float offsets within [0, 337920) bytes):
#define OFF_PSUM   0        // [64][256]
#define OFF_PSQ    16384    // [64][256]
#define OFF_SCALE  32768    // [256]
#define OFF_SHIFT  33024    // [256]
#define OFF_PART   33280    // [64][8][100]
#define BOFF_WT    337920ull                  // W_T bf16 [24][64 d][256 f] = 786,432
#define BOFF_WMT   1124352ull                 // WmT bf16 [112 c][512 k] = 114,688
#define BOFF_Q     1239040ull                 // q bf16 [64][8][500][64] = 32,768,000
#define BOFF_K     34007040ull                // k bf16 same
#define BOFF_VT    66775040ull                // v^T bf16 [64][8][64 d][512 n] = 33,554,432
#define BOFF_YM    100329472ull               // ymax_T bf16 [64][500][256] = 16,384,000
#define BOFF_O     BOFF_YM                    // o bf16 [64][500][512] = 32,768,000 (aliases ymax_T)
#define WS_NEED    133097472ull               // < 128 MiB

// ---------------- bf16 helpers (RNE) ----------------
__device__ __forceinline__ float blo(uint32_t u) { return __uint_as_float(u << 16); }
__device__ __forceinline__ float bhi(uint32_t u) { return __uint_as_float(u & 0xFFFF0000u); }
__device__ __forceinline__ uint32_t f2bf1(float f) {
  uint32_t x = __float_as_uint(f);
  return (x + 0x7FFFu + ((x >> 16) & 1u)) >> 16;
}
__device__ __forceinline__ uint32_t pack2(float a, float b) {
  return f2bf1(a) | (f2bf1(b) << 16);
}

typedef short bf16x8 __attribute__((ext_vector_type(8)));
typedef float f32x4  __attribute__((ext_vector_type(4)));
union UB { uint4 u; bf16x8 v; };

// XOR swizzle for [rows][64 bf16] LDS tiles (128 B rows): spreads the
// 16-lanes-same-column access across 8 distinct 16B slots (G4 fix).
__device__ __forceinline__ int swz(int row, int colElem) {
  return row * 128 + ((colElem * 2) ^ ((row & 7) << 4));
}

// =====================================================================
// Kernel 0: weight prep.
// blocks 0..23: Wq/Wk/Wv fp32 [8][256 f][64 d] -> bf16 WT[g][64 d][256 f]
// block 24:     Wm fp32 [512 k][100 c] -> bf16 WmT[112 c][512 k] (c-padded 0)
// =====================================================================
__global__ void k_prep(const float* __restrict__ Wq, const float* __restrict__ Wk,
                       const float* __restrict__ Wv, const float* __restrict__ Wm,
                       uint16_t* __restrict__ WT, uint16_t* __restrict__ WmT) {
  const int g = blockIdx.x;
  if (g < 24) {
    const int which = g >> 3, h = g & 7;
    const float* W = (which == 0 ? Wq : which == 1 ? Wk : Wv) + (size_t)h * NF * DH;
    uint16_t* dst = WT + (size_t)g * DH * NF;
    for (int idx = threadIdx.x; idx < NF * DH; idx += 256) {
      const int f = idx >> 6, d = idx & 63;
      dst[d * NF + f] = (uint16_t)f2bf1(W[idx]);
    }
  } else {
    for (int idx = threadIdx.x; idx < 112 * 512; idx += 256) {
      const int c = idx >> 9, k = idx & 511;
      WmT[idx] = (c < DMID) ? (uint16_t)f2bf1(Wm[k * DMID + c]) : (uint16_t)0;
    }
  }
}

// =====================================================================
// Kernel 1: conv1d + per-channel sum/sumsq (pre-BN) + maxpool(4), fused.
// grid (64 b, 16 fgroups of 16 filters), block 512 (1 thread = 1 pooled pos)
// Writes pre-BN pooled max TRANSPOSED as bf16 ymax_T[b][n][256 f]
// (32 B contiguous store per thread). BN+ReLU commute with max (scale>0).
// =====================================================================
__global__ __launch_bounds__(512) void k_conv(const float* __restrict__ x,
                                              const float* __restrict__ cw,
                                              uint16_t* __restrict__ ymaxT,
                                              float* __restrict__ psum,
                                              float* __restrict__ psq) {
  const int b = blockIdx.x;
  const int fg = blockIdx.y;
  const int tid = threadIdx.x;
  const int n = tid;                // pooled position
  const bool act = (n < NOUT);
  const float* xb = x + (size_t)b * (LL * CIN);

  float4 xw[16];
#pragma unroll
  for (int i = 0; i < 16; ++i) {
    const int p = 4 * n - 6 + i;
    if (act && p >= 0 && p < LL)
      xw[i] = *(const float4*)(xb + (size_t)p * CIN);
    else
      xw[i] = make_float4(0.f, 0.f, 0.f, 0.f);
  }

  __shared__ float redS[8][16];
  __shared__ float redQ[8][16];
  const int wave = tid >> 6, lane = tid & 63;
  uint32_t pw[8];
  float prev = 0.f;

  for (int fi = 0; fi < 16; ++fi) {
    const int f = fg * 16 + fi;
    const float* w = cw + (size_t)f * (CIN * KW);
    float wr[4][13];
#pragma unroll
    for (int c = 0; c < 4; ++c)
#pragma unroll
      for (int k = 0; k < 13; ++k) wr[c][k] = w[c * 13 + k];

    float a0 = 0.f, a1 = 0.f, a2 = 0.f, a3 = 0.f;
#pragma unroll
    for (int k = 0; k < 13; ++k) {
      const float4 p0 = xw[k + 0];
      const float4 p1 = xw[k + 1];
      const float4 p2 = xw[k + 2];
      const float4 p3 = xw[k + 3];
      a0 += wr[0][k] * p0.x + wr[1][k] * p0.y + wr[2][k] * p0.z + wr[3][k] * p0.w;
      a1 += wr[0][k] * p1.x + wr[1][k] * p1.y + wr[2][k] * p1.z + wr[3][k] * p1.w;
      a2 += wr[0][k] * p2.x + wr[1][k] * p2.y + wr[2][k] * p2.z + wr[3][k] * p2.w;
      a3 += wr[0][k] * p3.x + wr[1][k] * p3.y + wr[2][k] * p3.z + wr[3][k] * p3.w;
    }
    const float pm = fmaxf(fmaxf(a0, a1), fmaxf(a2, a3));
    if (fi & 1) pw[fi >> 1] = pack2(prev, pm); else prev = pm;

    float s  = act ? (a0 + a1 + a2 + a3) : 0.f;
    float q2 = act ? (a0 * a0 + a1 * a1 + a2 * a2 + a3 * a3) : 0.f;
#pragma unroll
    for (int off = 32; off >= 1; off >>= 1) {
      s  += __shfl_xor(s,  off, 64);
      q2 += __shfl_xor(q2, off, 64);
    }
    if (lane == 0) { redS[wave][fi] = s; redQ[wave][fi] = q2; }
  }
  if (act) {
    uint16_t* dst = ymaxT + ((size_t)b * NOUT + n) * NF + fg * 16;
    uint4 s0 = make_uint4(pw[0], pw[1], pw[2], pw[3]);
    uint4 s1 = make_uint4(pw[4], pw[5], pw[6], pw[7]);
    *(uint4*)dst = s0;
    *(uint4*)(dst + 8) = s1;
  }
  __syncthreads();
  if (tid < 16) {
    float s = 0.f;
#pragma unroll
    for (int wv = 0; wv < 8; ++wv) s += redS[wv][tid];
    psum[b * NF + fg * 16 + tid] = s;
  } else if (tid < 32) {
    float s = 0.f;
#pragma unroll
    for (int wv = 0; wv < 8; ++wv) s += redQ[wv][tid - 16];
    psq[b * NF + fg * 16 + (tid - 16)] = s;
  }
}

// =====================================================================
// Kernel 2: fold BN batch stats into per-channel scale/shift.
// =====================================================================
__global__ void k_stats(const float* __restrict__ psum, const float* __restrict__ psq,
                        const float* __restrict__ gamma, const float* __restrict__ beta,
                        float* __restrict__ scale, float* __restrict__ shift) {
  const int f = threadIdx.x;
  float s = 0.f, q = 0.f;
  for (int b = 0; b < NB; ++b) { s += psum[b * NF + f]; q += psq[b * NF + f]; }
  const float inv = 1.0f / (float)(NB * LL);
  const float mean = s * inv;
  const float var = q * inv - mean * mean;
  const float sc = gamma[f] * rsqrtf(var + 1e-5f);
  scale[f] = sc;
  shift[f] = beta[f] - mean * sc;
}

// =====================================================================
// Kernel 3: QKV projection, MFMA, LDS-free.
// grid (24 g = {q,k,v}x8 heads, 8 ntiles, 64 b) — g fastest so the 24
// blocks sharing one ymaxT slab dispatch adjacently (L2 reuse).
// block 256 = 4 waves; wave: 16 n-rows x 64 d.  K=256, 8 chunks of 32.
// A-frag = relu(scale*ymaxT+shift) built in-reg; B-frag = WT (L2-hot).
// V output stored TRANSPOSED: vbT[b][h][d][512 n] (PV B-operand layout).
// =====================================================================
__global__ __launch_bounds__(256, 4) void k_qkv(const uint16_t* __restrict__ ymaxT,
     const float* __restrict__ scale, const float* __restrict__ shift,
     const uint16_t* __restrict__ WT,
     const float* __restrict__ bq, const float* __restrict__ bk, const float* __restrict__ bv,
     uint16_t* __restrict__ qb, uint16_t* __restrict__ kb, uint16_t* __restrict__ vbT) {
  const int g  = blockIdx.x;
  const int nt = blockIdx.y;
  const int b  = blockIdx.z;
  const int which = g >> 3, h = g & 7;
  const int tid = threadIdx.x;
  const int wv = tid >> 6, l = tid & 63;
  const int lg = l >> 4, lq = l & 15;
  const int n0 = nt * 64 + wv * 16;
  const uint16_t* WTg = WT + (size_t)g * DH * NF;
  const float* bias = (which == 0 ? bq : which == 1 ? bk : bv) + h * DH;

  f32x4 acc[4] = {};   // 4 d-subtiles of 16

  const int an = n0 + lq;   // A row; rows >=500 read in-ws garbage, masked at store
  const uint16_t* abase = ymaxT + ((size_t)b * NOUT + an) * NF;

#pragma unroll
  for (int c = 0; c < 8; ++c) {          // f chunks of 32
    const int f0 = c * 32 + lg * 8;
    const uint4 ar = *(const uint4*)(abase + f0);
    const float4 s0 = *(const float4*)(scale + f0);
    const float4 s1 = *(const float4*)(scale + f0 + 4);
    const float4 h0 = *(const float4*)(shift + f0);
    const float4 h1 = *(const float4*)(shift + f0 + 4);
    UB a;
    a.u.x = pack2(fmaxf(s0.x * blo(ar.x) + h0.x, 0.f), fmaxf(s0.y * bhi(ar.x) + h0.y, 0.f));
    a.u.y = pack2(fmaxf(s0.z * blo(ar.y) + h0.z, 0.f), fmaxf(s0.w * bhi(ar.y) + h0.w, 0.f));
    a.u.z = pack2(fmaxf(s1.x * blo(ar.z) + h1.x, 0.f), fmaxf(s1.y * bhi(ar.z) + h1.y, 0.f));
    a.u.w = pack2(fmaxf(s1.z * blo(ar.w) + h1.z, 0.f), fmaxf(s1.w * bhi(ar.w) + h1.w, 0.f));
#pragma unroll
    for (int t = 0; t < 4; ++t) {
      UB bfr;
      bfr.u = *(const uint4*)(WTg + (size_t)(16 * t + lq) * NF + f0);
      acc[t] = __builtin_amdgcn_mfma_f32_16x16x32_bf16(a.v, bfr.v, acc[t], 0, 0, 0);
    }
  }

  // epilogue: bias + store (D: col d = 16t+lq, row n = n0+4*lg+r)
  if (which < 2) {
    uint16_t* out = (which == 0 ? qb : kb) + (size_t)(b * NH + h) * NOUT * DH;
#pragma unroll
    for (int t = 0; t < 4; ++t) {
      const int d = 16 * t + lq;
      const float bb = bias[d];
#pragma unroll
      for (int r = 0; r < 4; ++r) {
        const int nn = n0 + 4 * lg + r;
        if (nn < NOUT) out[(size_t)nn * DH + d] = (uint16_t)f2bf1(acc[t][r] + bb);
      }
    }
  } else {
    uint16_t* out = vbT + (size_t)(b * NH + h) * DH * 512;
#pragma unroll
    for (int t = 0; t < 4; ++t) {
      const int d = 16 * t + lq;
      const float bb = bias[d];
#pragma unroll
      for (int r = 0; r < 4; ++r) {
        const int nn = n0 + 4 * lg + r;
        if (nn < NOUT) out[(size_t)d * 512 + nn] = (uint16_t)f2bf1(acc[t][r] + bb);
      }
    }
  }
}

// =====================================================================
// Kernel 4: fused attention, MFMA flash-style.
// grid (8 qtiles, 8 h, 64 b), block 256 = 4 waves; wave owns 16 q-rows.
// Swapped QK^T: S^T = mfma(K, Q) -> per-lane key-local softmax.
// P packed to LDS bf16 (A-layout for PV); V^T tile from vbT (B-layout).
// LDS 24 KB, XOR-swizzled. Bias inline: (4|m-n|+3)/1999.
// =====================================================================
__global__ __launch_bounds__(256, 4) void k_attn(const uint16_t* __restrict__ qb,
                                                 const uint16_t* __restrict__ kb,
                                                 const uint16_t* __restrict__ vbT,
                                                 uint16_t* __restrict__ ob) {
  const int qt = blockIdx.x;
  const int h  = blockIdx.y;
  const int b  = blockIdx.z;
  const int tid = threadIdx.x;
  const int wv = tid >> 6, l = tid & 63;
  const int lg = l >> 4, lq = l & 15;

  __shared__ char smem[24576];
  char* Ks = smem;                       // K tile  [64 key][64 d] bf16, swizzled
  char* Vs = smem + 8192;                // V^T tile [64 d][64 key] bf16, swizzled
  char* Ps = smem + 16384 + wv * 2048;   // P tile  [16 q][64 key] bf16, swizzled

  const size_t qkbase = (size_t)(b * NH + h) * NOUT * DH;
  const size_t vbase  = (size_t)(b * NH + h) * DH * 512;
  const int q0 = qt * 64 + wv * 16;

  // Q B-fragments (held in regs for all 8 KV tiles)
  bf16x8 qf[2];
  {
    const int qn = min(q0 + lq, NOUT - 1);
    const uint16_t* src = qb + qkbase + (size_t)qn * DH + lg * 8;
    UB t0, t1;
    t0.u = *(const uint4*)src;
    t1.u = *(const uint4*)(src + 32);
    qf[0] = t0.v; qf[1] = t1.v;
  }

  f32x4 oacc[4] = {};
  float m = -1e30f, lsum = 0.f;
  const int nq = q0 + lq;

  for (int kt = 0; kt < 8; ++kt) {
    const int kv0 = kt * 64;
    __syncthreads();   // previous tile fully consumed
    {
      const int r = tid >> 2, cc = (tid & 3) * 16;
      const int kn = min(kv0 + r, NOUT - 1);
      const uint16_t* ksrc = kb + qkbase + (size_t)kn * DH + cc;
      uint4 ka = *(const uint4*)ksrc;
      uint4 kb4 = *(const uint4*)(ksrc + 8);
      *(uint4*)(Ks + swz(r, cc))     = ka;
      *(uint4*)(Ks + swz(r, cc + 8)) = kb4;
      const uint16_t* vsrc = vbT + vbase + (size_t)r * 512 + kv0 + cc;
      uint4 va = *(const uint4*)vsrc;
      uint4 vb4 = *(const uint4*)(vsrc + 8);
      *(uint4*)(Vs + swz(r, cc))     = va;
      *(uint4*)(Vs + swz(r, cc + 8)) = vb4;
    }
    __syncthreads();

    // QK^T (swapped): sacc[s] = S^T subtile, lane: key=kv0+16s+4lg+r, q=q0+lq
    f32x4 sacc[4] = {};
#pragma unroll
    for (int c = 0; c < 2; ++c)
#pragma unroll
      for (int s = 0; s < 4; ++s) {
        UB kf;
        kf.u = *(const uint4*)(Ks + swz(16 * s + lq, 32 * c + 8 * lg));
        sacc[s] = __builtin_amdgcn_mfma_f32_16x16x32_bf16(kf.v, qf[c], sacc[s], 0, 0, 0);
      }

    // online softmax; sacc reused in-place as P storage (VGPR saver)
    float tmax = -1e30f;
#pragma unroll
    for (int s = 0; s < 4; ++s)
#pragma unroll
      for (int r = 0; r < 4; ++r) {
        const int nk = kv0 + 16 * s + 4 * lg + r;
        float val = sacc[s][r] * 0.125f -
                    (4.0f * fabsf((float)(nq - nk)) + 3.0f) * (1.0f / 1999.0f);
        if (nk >= NOUT) val = -1e30f;
        sacc[s][r] = val;
        tmax = fmaxf(tmax, val);
      }
    tmax = fmaxf(tmax, __shfl_xor(tmax, 16, 64));
    tmax = fmaxf(tmax, __shfl_xor(tmax, 32, 64));
    const float mnew = fmaxf(m, tmax);
    const float corr = __expf(m - mnew);
    m = mnew;
    float ls = 0.f;
#pragma unroll
    for (int s = 0; s < 4; ++s)
#pragma unroll
      for (int r = 0; r < 4; ++r) {
        const float pv = __expf(sacc[s][r] - mnew);
        sacc[s][r] = pv;
        ls += pv;
      }
    ls += __shfl_xor(ls, 16, 64);
    ls += __shfl_xor(ls, 32, 64);
    lsum = lsum * corr + ls;

    // write P (bf16, A-layout: row q=lq, keys 16s+4lg..+3 packed b64)
#pragma unroll
    for (int s = 0; s < 4; ++s) {
      uint2 w;
      w.x = pack2(sacc[s][0], sacc[s][1]);
      w.y = pack2(sacc[s][2], sacc[s][3]);
      *(uint2*)(Ps + swz(lq, 16 * s + 4 * lg)) = w;
    }

    // rescale O by per-row corr (row q_local=4lg+r lives at lane 4lg+r)
    float cr[4];
#pragma unroll
    for (int r = 0; r < 4; ++r) cr[r] = __shfl(corr, 4 * lg + r, 64);
#pragma unroll
    for (int t = 0; t < 4; ++t)
#pragma unroll
      for (int r = 0; r < 4; ++r) oacc[t][r] *= cr[r];

    // PV: oacc[t] += P(16q x key) * B(key x 16d) from V^T tile
#pragma unroll
    for (int c = 0; c < 2; ++c) {
      UB pf;
      pf.u = *(const uint4*)(Ps + swz(lq, 32 * c + 8 * lg));
#pragma unroll
      for (int t = 0; t < 4; ++t) {
        UB vf;
        vf.u = *(const uint4*)(Vs + swz(16 * t + lq, 32 * c + 8 * lg));
        oacc[t] = __builtin_amdgcn_mfma_f32_16x16x32_bf16(pf.v, vf.v, oacc[t], 0, 0, 0);
      }
    }
  }

  // epilogue: 1/lsum per q-row, store o[b][n][h*64+d]
  const float inv = 1.0f / lsum;
  float invr[4];
#pragma unroll
  for (int r = 0; r < 4; ++r) invr[r] = __shfl(inv, 4 * lg + r, 64);
#pragma unroll
  for (int t = 0; t < 4; ++t) {
    const int d = 16 * t + lq;
#pragma unroll
    for (int r = 0; r < 4; ++r) {
      const int nn = q0 + 4 * lg + r;
      if (nn < NOUT)
        ob[((size_t)b * NOUT + nn) * (NH * DH) + h * DH + d] =
            (uint16_t)f2bf1(oacc[t][r] * invr[r]);
    }
  }
}

// =====================================================================
// Kernel 5: m = relu(o @ Wm + bm); position-sum -> part[b][nt][100].
// MFMA, LDS-free GEMM. grid (8 nt, 64 b), block 256 = 4 waves;
// wave: 16 n-rows x 112 c (7 subtiles), K=512 in 16 chunks.
// Column sums via shfl-reduce + per-wave LDS rows (deterministic).
// =====================================================================
__global__ __launch_bounds__(256, 4) void k_mhl(const uint16_t* __restrict__ ob,
                                                const uint16_t* __restrict__ WmT,
                                                const float* __restrict__ bm,
                                                float* __restrict__ part) {
  const int nt = blockIdx.x;
  const int b  = blockIdx.y;
  const int tid = threadIdx.x;
  const int wv = tid >> 6, l = tid & 63;
  const int lg = l >> 4, lq = l & 15;
  const int n0 = nt * 64 + wv * 16;

  __shared__ float lfeat[4][112];

  f32x4 acc[7] = {};
  const int an = min(n0 + lq, NOUT - 1);   // clamp (dup row excluded by mask below)
  const uint16_t* abase = ob + ((size_t)b * NOUT + an) * (NH * DH);

  for (int kc = 0; kc < 16; ++kc) {
    const int k0 = kc * 32 + lg * 8;
    UB a;
    a.u = *(const uint4*)(abase + k0);
#pragma unroll
    for (int t = 0; t < 7; ++t) {
      UB bfr;
      bfr.u = *(const uint4*)(WmT + (size_t)(16 * t + lq) * 512 + k0);
      acc[t] = __builtin_amdgcn_mfma_f32_16x16x32_bf16(a.v, bfr.v, acc[t], 0, 0, 0);
    }
  }

#pragma unroll
  for (int t = 0; t < 7; ++t) {
    const int c = 16 * t + lq;
    const float bb = (c < DMID) ? bm[c] : 0.f;
    float s = 0.f;
#pragma unroll
    for (int r = 0; r < 4; ++r) {
      const int nn = n0 + 4 * lg + r;
      if (nn < NOUT) s += fmaxf(acc[t][r] + bb, 0.f);
    }
    s += __shfl_xor(s, 16, 64);
    s += __shfl_xor(s, 32, 64);
    if (lg == 0) lfeat[wv][c] = s;
  }
  __syncthreads();
  if (tid < DMID)
    part[((size_t)b * 8 + nt) * DMID + tid] =
        lfeat[0][tid] + lfeat[1][tid] + lfeat[2][tid] + lfeat[3][tid];
}

// =====================================================================
// Kernel 6: final readout: sum partials, normalize over 100 feats, @Wo+bo.
// =====================================================================
__global__ void k_head(const float* __restrict__ part, const float* __restrict__ Wo,
                       const float* __restrict__ bo, float* __restrict__ out) {
  const int b = threadIdx.x;  // 64 threads
  float s1 = 0.f;
  for (int c = 0; c < DMID; ++c) {
    float v = 0.f;
    for (int t = 0; t < 8; ++t) v += part[((size_t)b * 8 + t) * DMID + c];
    s1 += v;
  }
  const float mean = s1 / (float)DMID;
  float s2 = 0.f;
  for (int c = 0; c < DMID; ++c) {
    float v = 0.f;
    for (int t = 0; t < 8; ++t) v += part[((size_t)b * 8 + t) * DMID + c];
    const float d = v - mean;
    s2 += d * d;
  }
  const float inv = 1.0f / (sqrtf(s2 / (float)DMID) + 1e-6f);
  float o0 = bo[0], o1 = bo[1];
  for (int c = 0; c < DMID; ++c) {
    float v = 0.f;
    for (int t = 0; t < 8; ++t) v += part[((size_t)b * 8 + t) * DMID + c];
    const float nz = (v - mean) * inv;
    o0 += nz * Wo[c * 2 + 0];
    o1 += nz * Wo[c * 2 + 1];
  }
  out[b * 2 + 0] = o0;
  out[b * 2 + 1] = o1;
}

// =====================================================================
extern "C" void kernel_launch(void* const* d_in, const int* in_sizes, int n_in,
                              void* d_out, int out_size, void* d_ws, size_t ws_size,
                              hipStream_t stream) {
  (void)in_sizes; (void)n_in; (void)out_size;
  const float* x     = (const float*)d_in[0];
  const float* cw    = (const float*)d_in[1];
  const float* gamma = (const float*)d_in[2];
  const float* beta  = (const float*)d_in[3];
  const float* Wq    = (const float*)d_in[4];
  const float* bq    = (const float*)d_in[5];
  const float* Wk    = (const float*)d_in[6];
  const float* bk    = (const float*)d_in[7];
  const float* Wv    = (const float*)d_in[8];
  const float* bv    = (const float*)d_in[9];
  const float* Wm    = (const float*)d_in[10];
  const float* bm    = (const float*)d_in[11];
  const float* Wo    = (const float*)d_in[12];
  const float* bo    = (const float*)d_in[13];
  float* out = (float*)d_out;

  if (ws_size < WS_NEED) return;  // ws too small: fail loudly (poison stays)

  float* wsf = (float*)d_ws;
  float* psum  = wsf + OFF_PSUM;
  float* psq   = wsf + OFF_PSQ;
  float* scale = wsf + OFF_SCALE;
  float* shift = wsf + OFF_SHIFT;
  float* partf = wsf + OFF_PART;
  uint16_t* WTb   = (uint16_t*)((char*)d_ws + BOFF_WT);
  uint16_t* WmT   = (uint16_t*)((char*)d_ws + BOFF_WMT);
  uint16_t* qbuf  = (uint16_t*)((char*)d_ws + BOFF_Q);
  uint16_t* kbuf  = (uint16_t*)((char*)d_ws + BOFF_K);
  uint16_t* vbT   = (uint16_t*)((char*)d_ws + BOFF_VT);
  uint16_t* ymaxT = (uint16_t*)((char*)d_ws + BOFF_YM);
  uint16_t* obuf  = (uint16_t*)((char*)d_ws + BOFF_O);   // aliases ymaxT (dead by then)

  k_prep <<<25, 256, 0, stream>>>(Wq, Wk, Wv, Wm, WTb, WmT);
  k_conv <<<dim3(NB, 16), 512, 0, stream>>>(x, cw, ymaxT, psum, psq);
  k_stats<<<1, NF, 0, stream>>>(psum, psq, gamma, beta, scale, shift);
  k_qkv  <<<dim3(24, 8, NB), 256, 0, stream>>>(ymaxT, scale, shift, WTb, bq, bk, bv,
                                               qbuf, kbuf, vbT);
  k_attn <<<dim3(8, NH, NB), 256, 0, stream>>>(qbuf, kbuf, vbT, obuf);
  k_mhl  <<<dim3(8, NB), 256, 0, stream>>>(obuf, WmT, bm, partf);
  k_head <<<1, NB, 0, stream>>>(partf, Wo, bo, out);
}